// Round 1
// baseline (1308.286 us; speedup 1.0000x reference)
//
#include <hip/hip_runtime.h>
#include <math.h>

// Problem constants
// x: (B=16, N=32, H=32, W=32, A=16) f32
// w: (K=3, K=3, N=32, A=16, M=32, D=16) f32  == flat [klna=4608][md=512]
// outputs: nqk (16,32,3,3,32,15,15) then ln_out (16,32,15,15,16), concatenated.
#define P_TOTAL 3600     // B * 15 * 15
#define KLNA    4608
#define OUTOFF  33177600 // nqk element count

// ---------------------------------------------------------------------------
// Kernel A: v_raw GEMM.  v[p][md] = (1/32) * sum_i patch[p][i] * W[i][md]
// Tile: 32 positions x 128 md cols, Kt=32. 256 threads, acc 4x4 per thread.
// ---------------------------------------------------------------------------
__global__ __launch_bounds__(256) void gemm_v_kernel(
    const float* __restrict__ x, const float* __restrict__ w,
    float* __restrict__ v)
{
    __shared__ __align__(16) float As[32 * 33];   // [kk][p], pad 33
    __shared__ __align__(16) float Bs[32 * 128];  // [kk][j]
    const int t  = threadIdx.x;
    const int n0 = blockIdx.x * 128;
    const int P0 = blockIdx.y * 32;

    // A-staging role: thread handles (kk = t&31, pp = t>>5 + 8*it)
    const int kkA = t & 31;
    const int ppA = t >> 5;
    int pbaseA[4];
    #pragma unroll
    for (int it = 0; it < 4; ++it) {
        int p = P0 + ppA + it * 8;
        bool ok = p < P_TOTAL;
        int pc = ok ? p : 0;
        int bb = pc / 225, rem = pc - bb * 225;
        int ho = rem / 15, wo = rem - ho * 15;
        // base = b*524288 + (2*ho)*512 + (2*wo)*16
        pbaseA[it] = ok ? (bb * 524288 + ho * 1024 + wo * 32) : -1;
    }
    const int jB  = t & 127;
    const int kB0 = t >> 7;   // 0..1

    float acc[4][4];
    #pragma unroll
    for (int i = 0; i < 4; ++i)
        #pragma unroll
        for (int j = 0; j < 4; ++j) acc[i][j] = 0.f;

    const int tj = t & 31;   // j0 = tj*4
    const int tp = t >> 5;   // p0 = tp*4

    for (int k0 = 0; k0 < KLNA; k0 += 32) {
        // ---- stage A tile (gather from x) ----
        {
            int i0 = k0 + kkA;                // klna index
            int aa = i0 & 15;
            int nn = (i0 >> 4) & 31;
            int kl = i0 >> 9;                 // 0..8
            int kk_ = kl / 3, ll_ = kl - kk_ * 3;
            int off = nn * 16384 + kk_ * 512 + ll_ * 16 + aa;
            #pragma unroll
            for (int it = 0; it < 4; ++it) {
                int pp = ppA + it * 8;
                float val = (pbaseA[it] >= 0) ? x[pbaseA[it] + off] : 0.f;
                As[kkA * 33 + pp] = val;
            }
        }
        // ---- stage B tile (contiguous rows of w) ----
        #pragma unroll
        for (int it = 0; it < 16; ++it) {
            int kk = kB0 + it * 2;
            Bs[kk * 128 + jB] = w[(size_t)(k0 + kk) * 512 + n0 + jB];
        }
        __syncthreads();
        // ---- compute ----
        #pragma unroll
        for (int kk = 0; kk < 32; ++kk) {
            float4 bv = *reinterpret_cast<const float4*>(&Bs[kk * 128 + tj * 4]);
            float bj[4] = {bv.x, bv.y, bv.z, bv.w};
            float ai[4];
            #pragma unroll
            for (int i = 0; i < 4; ++i) ai[i] = As[kk * 33 + tp * 4 + i];
            #pragma unroll
            for (int i = 0; i < 4; ++i)
                #pragma unroll
                for (int j = 0; j < 4; ++j)
                    acc[i][j] = fmaf(ai[i], bj[j], acc[i][j]);
        }
        __syncthreads();
    }
    const float s = 1.0f / 32.0f;   // qk = 1/M_OUT
    #pragma unroll
    for (int i = 0; i < 4; ++i) {
        int p = P0 + tp * 4 + i;
        if (p < P_TOTAL) {
            float4 o = make_float4(acc[i][0] * s, acc[i][1] * s,
                                   acc[i][2] * s, acc[i][3] * s);
            *reinterpret_cast<float4*>(&v[(size_t)p * 512 + n0 + tj * 4]) = o;
        }
    }
}

// ---------------------------------------------------------------------------
// Kernel B: squash (over d, per (p,m)) in-place on v, then LayerNorm -> out.
// One thread per (p, m). 3600*32 = 115200 threads = 450 blocks x 256.
// ---------------------------------------------------------------------------
__global__ __launch_bounds__(256) void squash_ln_kernel(
    float* __restrict__ v, const float* __restrict__ gamma,
    const float* __restrict__ beta, float* __restrict__ out)
{
    int pm = blockIdx.x * 256 + threadIdx.x;  // 0..115199
    int p = pm >> 5, m = pm & 31;
    float vv[16];
    #pragma unroll
    for (int q = 0; q < 4; ++q) {
        float4 t4 = *reinterpret_cast<const float4*>(&v[(size_t)p * 512 + m * 16 + q * 4]);
        vv[4*q+0] = t4.x; vv[4*q+1] = t4.y; vv[4*q+2] = t4.z; vv[4*q+3] = t4.w;
    }
    float sq = 0.f;
    #pragma unroll
    for (int d = 0; d < 16; ++d) sq = fmaf(vv[d], vv[d], sq);
    // sq/(1+sq) * v / sqrt(sq) == v * sqrt(sq)/(1+sq)
    float scale = sqrtf(sq) / (1.0f + sq);
    #pragma unroll
    for (int d = 0; d < 16; ++d) vv[d] *= scale;
    #pragma unroll
    for (int q = 0; q < 4; ++q) {
        float4 o = make_float4(vv[4*q], vv[4*q+1], vv[4*q+2], vv[4*q+3]);
        *reinterpret_cast<float4*>(&v[(size_t)p * 512 + m * 16 + q * 4]) = o;
    }
    float mu = 0.f;
    #pragma unroll
    for (int d = 0; d < 16; ++d) mu += vv[d];
    mu *= (1.0f / 16.0f);
    float var = 0.f;
    #pragma unroll
    for (int d = 0; d < 16; ++d) { float c = vv[d] - mu; var = fmaf(c, c, var); }
    var *= (1.0f / 16.0f);
    float rstd = rsqrtf(var + 1e-5f);
    int b = p / 225, hw = p - b * 225;
    size_t ob = (size_t)OUTOFF + (size_t)b * 115200 + (size_t)m * 3600 + (size_t)hw * 16;
    #pragma unroll
    for (int q = 0; q < 4; ++q) {
        float4 o;
        o.x = (vv[4*q+0] - mu) * rstd * gamma[4*q+0] + beta[4*q+0];
        o.y = (vv[4*q+1] - mu) * rstd * gamma[4*q+1] + beta[4*q+1];
        o.z = (vv[4*q+2] - mu) * rstd * gamma[4*q+2] + beta[4*q+2];
        o.w = (vv[4*q+3] - mu) * rstd * gamma[4*q+3] + beta[4*q+3];
        *reinterpret_cast<float4*>(&out[ob + 4 * q]) = o;
    }
}

// ---------------------------------------------------------------------------
// Kernel C: nqk[p][n,k,l,m] = sum_d ( sum_a patch[p][n,k,l,a]*w[k,l,n,a,m,d] ) * v[p,m,d]
// Block: 32 positions, 256 threads = 32 m-lanes x 8 p-groups (4 p each).
// Loop over kln (split into 8 chunks across blockIdx.y for occupancy).
// W_kln staged in LDS transposed [a][d][m] (+pad) -> conflict-free m-lane reads.
// ---------------------------------------------------------------------------
__global__ __launch_bounds__(256) void nqk_kernel(
    const float* __restrict__ x, const float* __restrict__ w,
    const float* __restrict__ v, float* __restrict__ out)
{
    __shared__ __align__(16) float Wl[16 * 528];  // [a][d*33 + m]
    __shared__ __align__(16) float pa[512];       // [pl][a]
    __shared__ int pbase_s[32];
    __shared__ int obase_s[32];
    const int t  = threadIdx.x;
    const int P0 = blockIdx.x * 32;
    const int kc = blockIdx.y;   // 0..7, 36 klns each

    if (t < 32) {
        int p = P0 + t;
        if (p < P_TOTAL) {
            int bb = p / 225, rem = p - bb * 225;
            int ho = rem / 15, wo = rem - ho * 15;
            pbase_s[t] = bb * 524288 + ho * 1024 + wo * 32;
            obase_s[t] = bb * 2073600 + ho * 15 + wo;
        } else { pbase_s[t] = 0; obase_s[t] = -1; }
    }
    const int m  = t & 31;
    const int pg = t >> 5;
    float vreg[4][16];
    #pragma unroll
    for (int i = 0; i < 4; ++i) {
        int p = P0 + pg * 4 + i;
        if (p < P_TOTAL) {
            #pragma unroll
            for (int q = 0; q < 4; ++q) {
                float4 t4 = *reinterpret_cast<const float4*>(&v[(size_t)p * 512 + m * 16 + q * 4]);
                vreg[i][4*q+0] = t4.x; vreg[i][4*q+1] = t4.y;
                vreg[i][4*q+2] = t4.z; vreg[i][4*q+3] = t4.w;
            }
        } else {
            #pragma unroll
            for (int d = 0; d < 16; ++d) vreg[i][d] = 0.f;
        }
    }
    __syncthreads();

    for (int kidx = kc * 36; kidx < kc * 36 + 36; ++kidx) {
        int nn = kidx & 31;
        int kl = kidx >> 5;
        int kk_ = kl / 3, ll_ = kl - kk_ * 3;
        const float* wk = w + (size_t)kidx * 8192;
        // stage W_kln transposed: [a][d][m] with d-row pad 33
        #pragma unroll
        for (int it = 0; it < 32; ++it) {
            int e = t + it * 256;
            int a_ = e >> 9, r = e & 511, mm = r >> 4, dd = r & 15;
            Wl[a_ * 528 + dd * 33 + mm] = wk[e];
        }
        // stage patch tile [pl][a]
        int xoff = nn * 16384 + kk_ * 512 + ll_ * 16;
        #pragma unroll
        for (int it = 0; it < 2; ++it) {
            int e = t + it * 256;
            int pl = e >> 4, aa = e & 15;
            pa[e] = x[pbase_s[pl] + xoff + aa];
        }
        __syncthreads();
        float pr[4][16];
        #pragma unroll
        for (int i = 0; i < 4; ++i) {
            int pl = pg * 4 + i;
            #pragma unroll
            for (int q = 0; q < 4; ++q) {
                float4 t4 = *reinterpret_cast<const float4*>(&pa[pl * 16 + q * 4]);
                pr[i][4*q+0] = t4.x; pr[i][4*q+1] = t4.y;
                pr[i][4*q+2] = t4.z; pr[i][4*q+3] = t4.w;
            }
        }
        float acc[4] = {0.f, 0.f, 0.f, 0.f};
        #pragma unroll
        for (int dd = 0; dd < 16; ++dd) {
            float wc[16];
            #pragma unroll
            for (int aa = 0; aa < 16; ++aa) wc[aa] = Wl[aa * 528 + dd * 33 + m];
            #pragma unroll
            for (int i = 0; i < 4; ++i) {
                float s = 0.f;
                #pragma unroll
                for (int aa = 0; aa < 16; ++aa) s = fmaf(pr[i][aa], wc[aa], s);
                acc[i] = fmaf(s, vreg[i][dd], acc[i]);
            }
        }
        int ooff = nn * 64800 + kk_ * 21600 + ll_ * 7200 + m * 225;
        #pragma unroll
        for (int i = 0; i < 4; ++i) {
            int ob = obase_s[pg * 4 + i];
            if (ob >= 0) out[(size_t)ob + ooff] = acc[i];
        }
        __syncthreads();
    }
}

// ---------------------------------------------------------------------------
extern "C" void kernel_launch(void* const* d_in, const int* in_sizes, int n_in,
                              void* d_out, int out_size, void* d_ws, size_t ws_size,
                              hipStream_t stream)
{
    const float* x     = (const float*)d_in[0];
    const float* w     = (const float*)d_in[1];
    const float* gamma = (const float*)d_in[2];
    const float* beta  = (const float*)d_in[3];
    float* out = (float*)d_out;
    float* vws = (float*)d_ws;   // 3600*512 floats = 7.37 MB

    dim3 gA(4, 113);             // 4 md-tiles x ceil(3600/32) p-tiles
    gemm_v_kernel<<<gA, 256, 0, stream>>>(x, w, vws);
    squash_ln_kernel<<<450, 256, 0, stream>>>(vws, gamma, beta, out);
    nqk_kernel<<<dim3(113, 8), 256, 0, stream>>>(x, w, vws, out);
}

// Round 2
// 752.488 us; speedup vs baseline: 1.7386x; 1.7386x over previous
//
#include <hip/hip_runtime.h>
#include <math.h>

// Problem constants
// x: (B=16, N=32, H=32, W=32, A=16) f32   -> 16.78M floats
// w: (K=3, K=3, N=32, A=16, M=32, D=16) f32 == flat [i=4608][md=512]
// outputs: nqk (16,32,3,3,32,15,15) then ln_out (16,32,15,15,16), concat.
#define P_TOTAL 3600     // B * 15 * 15
#define OUTOFF  33177600 // nqk element count

typedef unsigned short ushort_t;
typedef short s8v __attribute__((ext_vector_type(8)));     // 8 bf16 = 4 VGPR
typedef float f16v __attribute__((ext_vector_type(16)));   // MFMA 32x32 acc

// ws layout (new path)
#define V_OFF   0
#define V_BYTES 7372800ull                 // 3600*512*4
#define WT_OFF  7372800ull
#define WT_BYTES 9437184ull                // 288*512*32*2
#define X2_OFF  16809984ull
#define X2_BYTES 33554432ull               // 524288 px * 64B
#define WS_NEED (X2_OFF + X2_BYTES)        // 50,364,416

__device__ __forceinline__ ushort_t f2bf(float x) {
    unsigned u = __float_as_uint(x);
    u += 0x7FFFu + ((u >> 16) & 1u);       // RNE
    return (ushort_t)(u >> 16);
}
__device__ __forceinline__ float bf2f(unsigned h) {
    return __uint_as_float((h & 0xFFFFu) << 16);
}

// ---------------------------------------------------------------------------
// conv_x: x fp32 -> x2 [px][hi bf16 a0..15 | lo bf16 a0..15] (64B per pixel)
// px = ((b*32+n)*32+h)*32+w ; 524288 px
// ---------------------------------------------------------------------------
__global__ __launch_bounds__(256) void conv_x_kernel(
    const float* __restrict__ x, int4* __restrict__ x2)
{
    int px = blockIdx.x * 256 + threadIdx.x;   // grid exactly covers 524288
    const float4* xf = (const float4*)(x + (size_t)px * 16);
    float vv[16];
    #pragma unroll
    for (int q = 0; q < 4; ++q) {
        float4 t4 = xf[q];
        vv[4*q+0]=t4.x; vv[4*q+1]=t4.y; vv[4*q+2]=t4.z; vv[4*q+3]=t4.w;
    }
    ushort_t hi[16], lo[16];
    #pragma unroll
    for (int i = 0; i < 16; ++i) {
        hi[i] = f2bf(vv[i]);
        lo[i] = f2bf(vv[i] - bf2f(hi[i]));
    }
    unsigned hu[8], lu[8];
    #pragma unroll
    for (int j = 0; j < 8; ++j) {
        hu[j] = (unsigned)hi[2*j] | ((unsigned)hi[2*j+1] << 16);
        lu[j] = (unsigned)lo[2*j] | ((unsigned)lo[2*j+1] << 16);
    }
    int base = px * 4;
    x2[base+0] = make_int4(hu[0],hu[1],hu[2],hu[3]);
    x2[base+1] = make_int4(hu[4],hu[5],hu[6],hu[7]);
    x2[base+2] = make_int4(lu[0],lu[1],lu[2],lu[3]);
    x2[base+3] = make_int4(lu[4],lu[5],lu[6],lu[7]);
}

// ---------------------------------------------------------------------------
// conv_w: w fp32 [i=c*16+a][md] -> wt [c][md][hi a0..15 | lo a0..15] (64B)
// one block per chunk c (288 blocks)
// ---------------------------------------------------------------------------
__global__ __launch_bounds__(256) void conv_w_kernel(
    const float* __restrict__ w, int4* __restrict__ wt)
{
    __shared__ float wst[16 * 512];
    const int c = blockIdx.x, t = threadIdx.x;
    const float* wc = w + (size_t)c * 8192;
    #pragma unroll
    for (int it = 0; it < 32; ++it) wst[it * 256 + t] = wc[it * 256 + t];
    __syncthreads();
    for (int half = 0; half < 2; ++half) {
        int md = t + half * 256;
        ushort_t hi[16], lo[16];
        #pragma unroll
        for (int a = 0; a < 16; ++a) {
            float v = wst[a * 512 + md];
            hi[a] = f2bf(v);
            lo[a] = f2bf(v - bf2f(hi[a]));
        }
        unsigned hu[8], lu[8];
        #pragma unroll
        for (int j = 0; j < 8; ++j) {
            hu[j] = (unsigned)hi[2*j] | ((unsigned)hi[2*j+1] << 16);
            lu[j] = (unsigned)lo[2*j] | ((unsigned)lo[2*j+1] << 16);
        }
        int base = (c * 512 + md) * 4;
        wt[base+0] = make_int4(hu[0],hu[1],hu[2],hu[3]);
        wt[base+1] = make_int4(hu[4],hu[5],hu[6],hu[7]);
        wt[base+2] = make_int4(lu[0],lu[1],lu[2],lu[3]);
        wt[base+3] = make_int4(lu[4],lu[5],lu[6],lu[7]);
    }
}

// ---------------------------------------------------------------------------
// gemm_v_mfma: v[p][md] += (1/32) * sum_i patch[p][i]*W[i][md] via 32x32x16
// grid (2 md-halves, 29 p-blocks of 128, 8 k-splits of 36 chunks); atomics.
// Orientation: D[row=md][col=p];  A = W^T (rows md), B = patch^T (cols p).
// Split: D = Ah*Bh + Ah*Bl + Al*Bh  (drop lo*lo, ~2^-16)
// ---------------------------------------------------------------------------
__global__ __launch_bounds__(256) void gemm_v_mfma(
    const int4* __restrict__ x2, const int4* __restrict__ wt,
    float* __restrict__ v)
{
    const int t = threadIdx.x;
    const int l = t & 63, wv = t >> 6;
    const int g2 = l >> 5, lp = l & 31;
    const int mdb = blockIdx.x * 256 + wv * 64;   // wave's 2 m-tiles (64 md)
    const int pb  = blockIdx.y * 128;             // 4 p-tiles of 32
    const int c0  = blockIdx.z * 36;

    int pxq[4], pq[4]; bool pv[4];
    #pragma unroll
    for (int q = 0; q < 4; ++q) {
        int p = pb + q * 32 + lp;
        pv[q] = p < P_TOTAL; pq[q] = p;
        int pc = pv[q] ? p : 0;
        int bb = pc / 225, rem = pc - bb * 225;
        int ho = rem / 15, wo = rem - ho * 15;
        pxq[q] = bb * 32768 + ho * 64 + wo * 2;
    }
    f16v zero = 0.0f;
    f16v acc[2][4];
    #pragma unroll
    for (int mt = 0; mt < 2; ++mt)
        #pragma unroll
        for (int q = 0; q < 4; ++q) acc[mt][q] = zero;

    for (int c = c0; c < c0 + 36; ++c) {
        int n = c & 31, kl = c >> 5;
        int kk = kl / 3, ll = kl - kk * 3;
        int coff = n * 1024 + kk * 32 + ll;
        s8v Ah[2], Al[2];
        #pragma unroll
        for (int mt = 0; mt < 2; ++mt) {
            int ai = (c * 512 + mdb + mt * 32 + lp) * 4 + g2;
            Ah[mt] = __builtin_bit_cast(s8v, wt[ai]);
            Al[mt] = __builtin_bit_cast(s8v, wt[ai + 2]);
        }
        #pragma unroll
        for (int q = 0; q < 4; ++q) {
            int bi = (pxq[q] + coff) * 4 + g2;
            s8v Bh = __builtin_bit_cast(s8v, x2[bi]);
            s8v Bl = __builtin_bit_cast(s8v, x2[bi + 2]);
            #pragma unroll
            for (int mt = 0; mt < 2; ++mt) {
                acc[mt][q] = __builtin_amdgcn_mfma_f32_32x32x16_bf16(Ah[mt], Bh, acc[mt][q], 0, 0, 0);
                acc[mt][q] = __builtin_amdgcn_mfma_f32_32x32x16_bf16(Ah[mt], Bl, acc[mt][q], 0, 0, 0);
                acc[mt][q] = __builtin_amdgcn_mfma_f32_32x32x16_bf16(Al[mt], Bh, acc[mt][q], 0, 0, 0);
            }
        }
    }
    const float s = 1.0f / 32.0f;
    #pragma unroll
    for (int mt = 0; mt < 2; ++mt)
        #pragma unroll
        for (int q = 0; q < 4; ++q) {
            if (!pv[q]) continue;
            #pragma unroll
            for (int r = 0; r < 16; ++r) {
                int row = (r & 3) + 8 * (r >> 2) + 4 * g2;   // verified C/D map
                atomicAdd(&v[(size_t)pq[q] * 512 + mdb + mt * 32 + row],
                          acc[mt][q][r] * s);
            }
        }
}

// ---------------------------------------------------------------------------
// squash + LayerNorm (unchanged from baseline; v in-place, ln -> out tail)
// ---------------------------------------------------------------------------
__global__ __launch_bounds__(256) void squash_ln_kernel(
    float* __restrict__ v, const float* __restrict__ gamma,
    const float* __restrict__ beta, float* __restrict__ out)
{
    int pm = blockIdx.x * 256 + threadIdx.x;
    int p = pm >> 5, m = pm & 31;
    float vv[16];
    #pragma unroll
    for (int q = 0; q < 4; ++q) {
        float4 t4 = *reinterpret_cast<const float4*>(&v[(size_t)p * 512 + m * 16 + q * 4]);
        vv[4*q+0] = t4.x; vv[4*q+1] = t4.y; vv[4*q+2] = t4.z; vv[4*q+3] = t4.w;
    }
    float sq = 0.f;
    #pragma unroll
    for (int d = 0; d < 16; ++d) sq = fmaf(vv[d], vv[d], sq);
    float scale = sqrtf(sq) / (1.0f + sq);
    #pragma unroll
    for (int d = 0; d < 16; ++d) vv[d] *= scale;
    #pragma unroll
    for (int q = 0; q < 4; ++q) {
        float4 o = make_float4(vv[4*q], vv[4*q+1], vv[4*q+2], vv[4*q+3]);
        *reinterpret_cast<float4*>(&v[(size_t)p * 512 + m * 16 + q * 4]) = o;
    }
    float mu = 0.f;
    #pragma unroll
    for (int d = 0; d < 16; ++d) mu += vv[d];
    mu *= (1.0f / 16.0f);
    float var = 0.f;
    #pragma unroll
    for (int d = 0; d < 16; ++d) { float cdv = vv[d] - mu; var = fmaf(cdv, cdv, var); }
    var *= (1.0f / 16.0f);
    float rstd = rsqrtf(var + 1e-5f);
    int b = p / 225, hw = p - b * 225;
    size_t ob = (size_t)OUTOFF + (size_t)b * 115200 + (size_t)m * 3600 + (size_t)hw * 16;
    #pragma unroll
    for (int q = 0; q < 4; ++q) {
        float4 o;
        o.x = (vv[4*q+0] - mu) * rstd * gamma[4*q+0] + beta[4*q+0];
        o.y = (vv[4*q+1] - mu) * rstd * gamma[4*q+1] + beta[4*q+1];
        o.z = (vv[4*q+2] - mu) * rstd * gamma[4*q+2] + beta[4*q+2];
        o.w = (vv[4*q+3] - mu) * rstd * gamma[4*q+3] + beta[4*q+3];
        *reinterpret_cast<float4*>(&out[ob + 4 * q]) = o;
    }
}

// ---------------------------------------------------------------------------
// nqk_mfma: per chunk c=(kl,n): S^T tiles [32 md x 32 p] via 3 MFMAs, then
// nqk[p][c][m] = sum_d S*v with in-lane dot (v hoisted, packed bf16 regs)
// + one shfl_xor(32) pair.  grid (57 p-blocks of 64, 8 chunk-splits of 36).
// ---------------------------------------------------------------------------
__global__ __launch_bounds__(256) void nqk_mfma(
    const int4* __restrict__ x2, const int4* __restrict__ wt,
    const float* __restrict__ v, float* __restrict__ out)
{
    // vle[p][m*16 + pos(d)] ; pos swaps d-quads 1<->2 so each g2-half's
    // 8 needed d-values are one contiguous 16B read.
    __shared__ ushort_t vle[64][520];
    __shared__ int pxb[64], obas[64];
    const int t = threadIdx.x;
    const int l = t & 63, wvq = t >> 6;
    const int g2 = l >> 5, lp = l & 31;
    const int p0 = blockIdx.x * 64;
    const int c0 = blockIdx.y * 36;

    if (t < 64) {
        int p = p0 + t;
        if (p < P_TOTAL) {
            int bb = p / 225, rem = p - bb * 225;
            int ho = rem / 15, wo = rem - ho * 15;
            pxb[t]  = bb * 32768 + ho * 64 + wo * 2;
            obas[t] = bb * 2073600 + ho * 15 + wo;
        } else { pxb[t] = 0; obas[t] = 0; }
    }
    // stage squashed v -> bf16 LDS (quad-swapped d layout)
    #pragma unroll
    for (int it = 0; it < 32; ++it) {
        int f4  = it * 256 + t;                 // 0..8191 float4s
        int plc = f4 >> 7;
        int mdq = (f4 & 127) * 4;
        float4 t4 = *(const float4*)(v + ((size_t)(p0 + plc) * 512 + mdq));
        int mdp = (mdq & ~12) | ((mdq & 4) << 1) | ((mdq & 8) >> 1);
        unsigned u0 = (unsigned)f2bf(t4.x) | ((unsigned)f2bf(t4.y) << 16);
        unsigned u1 = (unsigned)f2bf(t4.z) | ((unsigned)f2bf(t4.w) << 16);
        *(uint2*)&vle[plc][mdp] = make_uint2(u0, u1);
    }
    __syncthreads();

    // hoist v into packed-bf16 registers: [i(MT)][q][m-half]
    uint4 vvp[4][2][2];
    int oq[2]; bool pvq[2]; int pxq[2];
    #pragma unroll
    for (int q = 0; q < 2; ++q) {
        int pl = q * 32 + lp;
        oq[q]  = obas[pl];
        pxq[q] = pxb[pl];
        pvq[q] = (p0 + pl) < P_TOTAL;
        #pragma unroll
        for (int i = 0; i < 4; ++i) {
            int MT = wvq * 4 + i;
            vvp[i][q][0] = *(const uint4*)&vle[pl][MT * 32 + g2 * 8];
            vvp[i][q][1] = *(const uint4*)&vle[pl][MT * 32 + 16 + g2 * 8];
        }
    }

    for (int c = c0; c < c0 + 36; ++c) {
        int n = c & 31, kl = c >> 5;
        int kk = kl / 3, ll = kl - kk * 3;
        int coff = n * 1024 + kk * 32 + ll;
        int koff = n * 64800 + kk * 21600 + ll * 7200;
        s8v Bh[2], Bl[2];
        #pragma unroll
        for (int q = 0; q < 2; ++q) {
            int bi = (pxq[q] + coff) * 4 + g2;
            Bh[q] = __builtin_bit_cast(s8v, x2[bi]);
            Bl[q] = __builtin_bit_cast(s8v, x2[bi + 2]);
        }
        #pragma unroll
        for (int i = 0; i < 4; ++i) {
            int MT = wvq * 4 + i;
            int ai = (c * 512 + MT * 32 + lp) * 4 + g2;
            s8v Ah = __builtin_bit_cast(s8v, wt[ai]);
            s8v Al = __builtin_bit_cast(s8v, wt[ai + 2]);
            #pragma unroll
            for (int q = 0; q < 2; ++q) {
                f16v acc = 0.0f;
                acc = __builtin_amdgcn_mfma_f32_32x32x16_bf16(Ah, Bh[q], acc, 0, 0, 0);
                acc = __builtin_amdgcn_mfma_f32_32x32x16_bf16(Ah, Bl[q], acc, 0, 0, 0);
                acc = __builtin_amdgcn_mfma_f32_32x32x16_bf16(Al, Bh[q], acc, 0, 0, 0);
                // epilogue: dot with v over this lane's 8 d's per m-half
                uint4 a0 = vvp[i][q][0], a1 = vvp[i][q][1];
                float s0, s1;
                s0  = acc[0] * bf2f(a0.x)        + acc[1] * bf2f(a0.x >> 16);
                s0 += acc[2] * bf2f(a0.y)        + acc[3] * bf2f(a0.y >> 16);
                s0 += acc[4] * bf2f(a0.z)        + acc[5] * bf2f(a0.z >> 16);
                s0 += acc[6] * bf2f(a0.w)        + acc[7] * bf2f(a0.w >> 16);
                s1  = acc[8] * bf2f(a1.x)        + acc[9] * bf2f(a1.x >> 16);
                s1 += acc[10] * bf2f(a1.y)       + acc[11] * bf2f(a1.y >> 16);
                s1 += acc[12] * bf2f(a1.z)       + acc[13] * bf2f(a1.z >> 16);
                s1 += acc[14] * bf2f(a1.w)       + acc[15] * bf2f(a1.w >> 16);
                float t0 = s0 + __shfl_xor(s0, 32);
                float t1 = s1 + __shfl_xor(s1, 32);
                float tot = g2 ? t1 : t0;
                if (pvq[q])
                    out[(size_t)oq[q] + koff + (size_t)(MT * 2 + g2) * 225] = tot;
            }
        }
    }
}

// ===========================================================================
// Fallback path (round-1 fp32 kernels) — used only if ws_size < WS_NEED
// ===========================================================================
#define KLNA 4608
__global__ __launch_bounds__(256) void gemm_v_kernel(
    const float* __restrict__ x, const float* __restrict__ w,
    float* __restrict__ v)
{
    __shared__ __align__(16) float As[32 * 33];
    __shared__ __align__(16) float Bs[32 * 128];
    const int t  = threadIdx.x;
    const int n0 = blockIdx.x * 128;
    const int P0 = blockIdx.y * 32;
    const int kkA = t & 31;
    const int ppA = t >> 5;
    int pbaseA[4];
    #pragma unroll
    for (int it = 0; it < 4; ++it) {
        int p = P0 + ppA + it * 8;
        bool ok = p < P_TOTAL;
        int pc = ok ? p : 0;
        int bb = pc / 225, rem = pc - bb * 225;
        int ho = rem / 15, wo = rem - ho * 15;
        pbaseA[it] = ok ? (bb * 524288 + ho * 1024 + wo * 32) : -1;
    }
    const int jB  = t & 127;
    const int kB0 = t >> 7;
    float acc[4][4];
    #pragma unroll
    for (int i = 0; i < 4; ++i)
        #pragma unroll
        for (int j = 0; j < 4; ++j) acc[i][j] = 0.f;
    const int tj = t & 31;
    const int tp = t >> 5;
    for (int k0 = 0; k0 < KLNA; k0 += 32) {
        {
            int i0 = k0 + kkA;
            int aa = i0 & 15;
            int nn = (i0 >> 4) & 31;
            int kl = i0 >> 9;
            int kk_ = kl / 3, ll_ = kl - kk_ * 3;
            int off = nn * 16384 + kk_ * 512 + ll_ * 16 + aa;
            #pragma unroll
            for (int it = 0; it < 4; ++it) {
                int pp = ppA + it * 8;
                float val = (pbaseA[it] >= 0) ? x[pbaseA[it] + off] : 0.f;
                As[kkA * 33 + pp] = val;
            }
        }
        #pragma unroll
        for (int it = 0; it < 16; ++it) {
            int kk = kB0 + it * 2;
            Bs[kk * 128 + jB] = w[(size_t)(k0 + kk) * 512 + n0 + jB];
        }
        __syncthreads();
        #pragma unroll
        for (int kk = 0; kk < 32; ++kk) {
            float4 bv = *reinterpret_cast<const float4*>(&Bs[kk * 128 + tj * 4]);
            float bj[4] = {bv.x, bv.y, bv.z, bv.w};
            float ai[4];
            #pragma unroll
            for (int i = 0; i < 4; ++i) ai[i] = As[kk * 33 + tp * 4 + i];
            #pragma unroll
            for (int i = 0; i < 4; ++i)
                #pragma unroll
                for (int j = 0; j < 4; ++j)
                    acc[i][j] = fmaf(ai[i], bj[j], acc[i][j]);
        }
        __syncthreads();
    }
    const float s = 1.0f / 32.0f;
    #pragma unroll
    for (int i = 0; i < 4; ++i) {
        int p = P0 + tp * 4 + i;
        if (p < P_TOTAL) {
            float4 o = make_float4(acc[i][0] * s, acc[i][1] * s,
                                   acc[i][2] * s, acc[i][3] * s);
            *reinterpret_cast<float4*>(&v[(size_t)p * 512 + n0 + tj * 4]) = o;
        }
    }
}

__global__ __launch_bounds__(256) void nqk_kernel(
    const float* __restrict__ x, const float* __restrict__ w,
    const float* __restrict__ v, float* __restrict__ out)
{
    __shared__ __align__(16) float Wl[16 * 528];
    __shared__ __align__(16) float pa[512];
    __shared__ int pbase_s[32];
    __shared__ int obase_s[32];
    const int t  = threadIdx.x;
    const int P0 = blockIdx.x * 32;
    const int kc = blockIdx.y;
    if (t < 32) {
        int p = P0 + t;
        if (p < P_TOTAL) {
            int bb = p / 225, rem = p - bb * 225;
            int ho = rem / 15, wo = rem - ho * 15;
            pbase_s[t] = bb * 524288 + ho * 1024 + wo * 32;
            obase_s[t] = bb * 2073600 + ho * 15 + wo;
        } else { pbase_s[t] = 0; obase_s[t] = -1; }
    }
    const int m  = t & 31;
    const int pg = t >> 5;
    float vreg[4][16];
    #pragma unroll
    for (int i = 0; i < 4; ++i) {
        int p = P0 + pg * 4 + i;
        if (p < P_TOTAL) {
            #pragma unroll
            for (int q = 0; q < 4; ++q) {
                float4 t4 = *reinterpret_cast<const float4*>(&v[(size_t)p * 512 + m * 16 + q * 4]);
                vreg[i][4*q+0] = t4.x; vreg[i][4*q+1] = t4.y;
                vreg[i][4*q+2] = t4.z; vreg[i][4*q+3] = t4.w;
            }
        } else {
            #pragma unroll
            for (int d = 0; d < 16; ++d) vreg[i][d] = 0.f;
        }
    }
    __syncthreads();
    for (int kidx = kc * 36; kidx < kc * 36 + 36; ++kidx) {
        int nn = kidx & 31;
        int kl = kidx >> 5;
        int kk_ = kl / 3, ll_ = kl - kk_ * 3;
        const float* wk = w + (size_t)kidx * 8192;
        #pragma unroll
        for (int it = 0; it < 32; ++it) {
            int e = t + it * 256;
            int a_ = e >> 9, r = e & 511, mm = r >> 4, dd = r & 15;
            Wl[a_ * 528 + dd * 33 + mm] = wk[e];
        }
        int xoff = nn * 16384 + kk_ * 512 + ll_ * 16;
        #pragma unroll
        for (int it = 0; it < 2; ++it) {
            int e = t + it * 256;
            int pl = e >> 4, aa = e & 15;
            pa[e] = x[pbase_s[pl] + xoff + aa];
        }
        __syncthreads();
        float pr[4][16];
        #pragma unroll
        for (int i = 0; i < 4; ++i) {
            int pl = pg * 4 + i;
            #pragma unroll
            for (int q = 0; q < 4; ++q) {
                float4 t4 = *reinterpret_cast<const float4*>(&pa[pl * 16 + q * 4]);
                pr[i][4*q+0] = t4.x; pr[i][4*q+1] = t4.y;
                pr[i][4*q+2] = t4.z; pr[i][4*q+3] = t4.w;
            }
        }
        float acc[4] = {0.f, 0.f, 0.f, 0.f};
        #pragma unroll
        for (int dd = 0; dd < 16; ++dd) {
            float wc[16];
            #pragma unroll
            for (int aa = 0; aa < 16; ++aa) wc[aa] = Wl[aa * 528 + dd * 33 + m];
            #pragma unroll
            for (int i = 0; i < 4; ++i) {
                float ssum = 0.f;
                #pragma unroll
                for (int aa = 0; aa < 16; ++aa) ssum = fmaf(pr[i][aa], wc[aa], ssum);
                acc[i] = fmaf(ssum, vreg[i][dd], acc[i]);
            }
        }
        int ooff = nn * 64800 + kk_ * 21600 + ll_ * 7200 + m * 225;
        #pragma unroll
        for (int i = 0; i < 4; ++i) {
            int ob = obase_s[pg * 4 + i];
            if (ob >= 0) out[(size_t)ob + ooff] = acc[i];
        }
        __syncthreads();
    }
}

// ---------------------------------------------------------------------------
extern "C" void kernel_launch(void* const* d_in, const int* in_sizes, int n_in,
                              void* d_out, int out_size, void* d_ws, size_t ws_size,
                              hipStream_t stream)
{
    const float* x     = (const float*)d_in[0];
    const float* w     = (const float*)d_in[1];
    const float* gamma = (const float*)d_in[2];
    const float* beta  = (const float*)d_in[3];
    float* out = (float*)d_out;
    char* ws = (char*)d_ws;

    if (ws_size >= WS_NEED) {
        float* vws = (float*)(ws + V_OFF);
        int4*  wt  = (int4*)(ws + WT_OFF);
        int4*  x2  = (int4*)(ws + X2_OFF);
        hipMemsetAsync(vws, 0, V_BYTES, stream);
        conv_x_kernel<<<2048, 256, 0, stream>>>(x, x2);
        conv_w_kernel<<<288, 256, 0, stream>>>(w, wt);
        gemm_v_mfma<<<dim3(2, 29, 8), 256, 0, stream>>>(x2, wt, vws);
        squash_ln_kernel<<<450, 256, 0, stream>>>(vws, gamma, beta, out);
        nqk_mfma<<<dim3(57, 8), 256, 0, stream>>>(x2, wt, vws, out);
    } else {
        float* vws = (float*)ws;
        dim3 gA(4, 113);
        gemm_v_kernel<<<gA, 256, 0, stream>>>(x, w, vws);
        squash_ln_kernel<<<450, 256, 0, stream>>>(vws, gamma, beta, out);
        nqk_kernel<<<dim3(113, 8), 256, 0, stream>>>(x, w, vws, out);
    }
}

// Round 4
// 750.632 us; speedup vs baseline: 1.7429x; 1.0025x over previous
//
#include <hip/hip_runtime.h>
#include <math.h>

// x: (B=16, N=32, H=32, W=32, A=16) f32 = 8,388,608 floats
// w: (3,3,32,16,32,16) f32 == [i=4608][md=512] ; chunk c = i>>4 (288 chunks)
// out: nqk (16,32,3,3,32,15,15) ++ ln_out (16,32,15,15,16)
#define P_TOTAL 3600
#define OUTOFF  33177600

typedef unsigned short ushort_t;
typedef short s8v __attribute__((ext_vector_type(8)));     // 8 bf16
typedef float f16v __attribute__((ext_vector_type(16)));   // 32x32 acc

// ws layout
#define V_OFF     0ull
#define V_BYTES   7372800ull                  // 3600*512*4
#define WT_OFF    7372800ull
#define WT_BYTES  9437184ull                  // 288*4*512*16B
#define X2_OFF    16809984ull
#define X2_BYTES  33554432ull                 // 524288 px * 64B
#define VB2_OFF   50364416ull
#define VB2_BYTES 3686400ull                  // 64*3600*16B
#define WS_VB2_NEED (VB2_OFF + VB2_BYTES)     // 54,050,816

__device__ __forceinline__ ushort_t f2bf(float x) {
    unsigned u = __float_as_uint(x);
    u += 0x7FFFu + ((u >> 16) & 1u);
    return (ushort_t)(u >> 16);
}
__device__ __forceinline__ float bf2f(unsigned h) {
    return __uint_as_float((h & 0xFFFFu) << 16);
}
__device__ __forceinline__ unsigned pk2(float a, float b) {
    return (unsigned)f2bf(a) | ((unsigned)f2bf(b) << 16);
}
__device__ __forceinline__ float bflo(unsigned u) { return __uint_as_float(u << 16); }
__device__ __forceinline__ float bfhi(unsigned u) { return __uint_as_float(u & 0xFFFF0000u); }

__device__ __forceinline__ void gload16(const void* g, void* l) {
    __builtin_amdgcn_global_load_lds(
        (const __attribute__((address_space(1))) unsigned int*)g,
        (__attribute__((address_space(3))) unsigned int*)l, 16, 0, 0);
}

// ---------------------------------------------------------------------------
// conv_x: x f32 -> x2 per-pixel 64B: [hi a0..7][hi a8..15][lo a0..7][lo a8..15]
// ---------------------------------------------------------------------------
__global__ __launch_bounds__(256) void conv_x_kernel(
    const float* __restrict__ x, int4* __restrict__ x2)
{
    int px = blockIdx.x * 256 + threadIdx.x;   // 524288 exact
    const float4* xf = (const float4*)(x + (size_t)px * 16);
    float vv[16];
    #pragma unroll
    for (int q = 0; q < 4; ++q) {
        float4 t4 = xf[q];
        vv[4*q+0]=t4.x; vv[4*q+1]=t4.y; vv[4*q+2]=t4.z; vv[4*q+3]=t4.w;
    }
    ushort_t hi[16], lo[16];
    #pragma unroll
    for (int i = 0; i < 16; ++i) {
        hi[i] = f2bf(vv[i]);
        lo[i] = f2bf(vv[i] - bf2f(hi[i]));
    }
    unsigned hu[8], lu[8];
    #pragma unroll
    for (int j = 0; j < 8; ++j) {
        hu[j] = (unsigned)hi[2*j] | ((unsigned)hi[2*j+1] << 16);
        lu[j] = (unsigned)lo[2*j] | ((unsigned)lo[2*j+1] << 16);
    }
    int base = px * 4;
    x2[base+0] = make_int4(hu[0],hu[1],hu[2],hu[3]);
    x2[base+1] = make_int4(hu[4],hu[5],hu[6],hu[7]);
    x2[base+2] = make_int4(lu[0],lu[1],lu[2],lu[3]);
    x2[base+3] = make_int4(lu[4],lu[5],lu[6],lu[7]);
}

// ---------------------------------------------------------------------------
// conv_w: w f32 [c*16+a][md] -> wt2 [c][s(hi/lo)][g2][md] of 16B (a 8g2..8g2+7)
// ---------------------------------------------------------------------------
__global__ __launch_bounds__(256) void conv_w_kernel(
    const float* __restrict__ w, int4* __restrict__ wt)
{
    __shared__ float wst[16 * 512];
    const int c = blockIdx.x, t = threadIdx.x;
    const float* wc = w + (size_t)c * 8192;
    #pragma unroll
    for (int it = 0; it < 32; ++it) wst[it * 256 + t] = wc[it * 256 + t];
    __syncthreads();
    #pragma unroll
    for (int half = 0; half < 2; ++half) {
        int md = t + half * 256;
        ushort_t hi[16], lo[16];
        #pragma unroll
        for (int a = 0; a < 16; ++a) {
            float v = wst[a * 512 + md];
            hi[a] = f2bf(v);
            lo[a] = f2bf(v - bf2f(hi[a]));
        }
        unsigned hu[8], lu[8];
        #pragma unroll
        for (int j = 0; j < 8; ++j) {
            hu[j] = (unsigned)hi[2*j] | ((unsigned)hi[2*j+1] << 16);
            lu[j] = (unsigned)lo[2*j] | ((unsigned)lo[2*j+1] << 16);
        }
        wt[(size_t)(c*4 + 0)*512 + md] = make_int4(hu[0],hu[1],hu[2],hu[3]);
        wt[(size_t)(c*4 + 1)*512 + md] = make_int4(hu[4],hu[5],hu[6],hu[7]);
        wt[(size_t)(c*4 + 2)*512 + md] = make_int4(lu[0],lu[1],lu[2],lu[3]);
        wt[(size_t)(c*4 + 3)*512 + md] = make_int4(lu[4],lu[5],lu[6],lu[7]);
    }
}

// ---------------------------------------------------------------------------
// gemm_v: v[p][md] = (1/32) sum_i patch*W.  128md x 128p tiles, full K.
// grid (4, 29). 4 waves: wave tile 64md x 64p. LDS double-buffered via
// global_load_lds. No atomics.
// ---------------------------------------------------------------------------
__global__ __launch_bounds__(256) void gemm_v_mfma(
    const int4* __restrict__ x2, const int4* __restrict__ wt,
    float* __restrict__ v)
{
    __shared__ int4 As[2][512];   // [buf][sg*128 + mdl]
    __shared__ int4 Bs[2][512];   // [buf][ib*256 + j*64 + pr]
    const int t  = threadIdx.x;
    const int l  = t & 63, wv = t >> 6;
    const int g2 = l >> 5, lp = l & 31;
    const int mdb = blockIdx.x * 128;
    const int pb  = blockIdx.y * 128;
    const int mdw = (wv & 1) * 64, pw = (wv >> 1) * 64;

    const int sgA  = t >> 7;         // 0..1
    const int mdlA = t & 127;
    const int prB  = t & 63;
    const int jB   = t >> 6;         // 0..3
    const int wbase = t & ~63;       // wave-uniform

    int pxS[2];
    #pragma unroll
    for (int ib = 0; ib < 2; ++ib) {
        int p = pb + ib * 64 + prB;
        int pc = p < P_TOTAL ? p : 0;
        int bb = pc / 225, rem = pc - bb * 225;
        int ho = rem / 15, wo = rem - ho * 15;
        pxS[ib] = bb * 32768 + ho * 64 + wo * 2;
    }

    f16v acc[2][2];
    #pragma unroll
    for (int mt = 0; mt < 2; ++mt)
        #pragma unroll
        for (int q = 0; q < 2; ++q) acc[mt][q] = 0.0f;

    auto STAGE = [&](int b, int c) {
        int n = c & 31, kl = c >> 5;
        int kk = kl / 3, ll = kl - kk * 3;
        int coff = n * 1024 + kk * 32 + ll;
        #pragma unroll
        for (int ia = 0; ia < 2; ++ia)
            gload16(&wt[(size_t)(c*4 + ia*2 + sgA)*512 + mdb + mdlA],
                    &As[b][ia*256 + wbase]);
        #pragma unroll
        for (int ib = 0; ib < 2; ++ib)
            gload16(&x2[(size_t)(pxS[ib] + coff)*4 + jB],
                    &Bs[b][ib*256 + wbase]);
    };

    STAGE(0, 0);
    int buf = 0;
    for (int c = 0; c < 288; ++c) {
        __syncthreads();
        if (c + 1 < 288) STAGE(buf ^ 1, c + 1);
        s8v Ah[2], Al[2];
        #pragma unroll
        for (int mt = 0; mt < 2; ++mt) {
            int mdl = mdw + mt * 32 + lp;
            Ah[mt] = __builtin_bit_cast(s8v, As[buf][g2*128 + mdl]);
            Al[mt] = __builtin_bit_cast(s8v, As[buf][(2+g2)*128 + mdl]);
        }
        #pragma unroll
        for (int q = 0; q < 2; ++q) {
            int pl = pw + q * 32 + lp;
            int ib = pl >> 6, pr = pl & 63;
            s8v Bh = __builtin_bit_cast(s8v, Bs[buf][ib*256 + g2*64 + pr]);
            s8v Bl = __builtin_bit_cast(s8v, Bs[buf][ib*256 + (2+g2)*64 + pr]);
            #pragma unroll
            for (int mt = 0; mt < 2; ++mt) {
                acc[mt][q] = __builtin_amdgcn_mfma_f32_32x32x16_bf16(Al[mt], Bh, acc[mt][q], 0, 0, 0);
                acc[mt][q] = __builtin_amdgcn_mfma_f32_32x32x16_bf16(Ah[mt], Bl, acc[mt][q], 0, 0, 0);
                acc[mt][q] = __builtin_amdgcn_mfma_f32_32x32x16_bf16(Ah[mt], Bh, acc[mt][q], 0, 0, 0);
            }
        }
        buf ^= 1;
    }

    const float sc = 1.0f / 32.0f;
    #pragma unroll
    for (int mt = 0; mt < 2; ++mt)
        #pragma unroll
        for (int q = 0; q < 2; ++q) {
            int p = pb + pw + q * 32 + lp;
            if (p >= P_TOTAL) continue;
            float* vp = v + (size_t)p*512 + mdb + mdw + mt*32 + 4*g2;
            #pragma unroll
            for (int qd = 0; qd < 4; ++qd) {
                float4 o = make_float4(acc[mt][q][4*qd+0]*sc, acc[mt][q][4*qd+1]*sc,
                                       acc[mt][q][4*qd+2]*sc, acc[mt][q][4*qd+3]*sc);
                *(float4*)(vp + 8*qd) = o;
            }
        }
}

// ---------------------------------------------------------------------------
// squash + LayerNorm; optionally emit vb2: bf16-packed v in epilogue layout
// vb2[((MT*2+g2)*2+u)*3600 + p] = uint4 of d-pairs for m=MT*2+u, half g2
// ---------------------------------------------------------------------------
template<bool VB2>
__global__ __launch_bounds__(256) void squash_ln_kernel(
    float* __restrict__ v, const float* __restrict__ gamma,
    const float* __restrict__ beta, float* __restrict__ out,
    uint4* __restrict__ vb2)
{
    int pm = blockIdx.x * 256 + threadIdx.x;
    int p = pm >> 5, m = pm & 31;
    float vv[16];
    #pragma unroll
    for (int q = 0; q < 4; ++q) {
        float4 t4 = *reinterpret_cast<const float4*>(&v[(size_t)p * 512 + m * 16 + q * 4]);
        vv[4*q+0] = t4.x; vv[4*q+1] = t4.y; vv[4*q+2] = t4.z; vv[4*q+3] = t4.w;
    }
    float sq = 0.f;
    #pragma unroll
    for (int d = 0; d < 16; ++d) sq = fmaf(vv[d], vv[d], sq);
    float scale = sqrtf(sq) / (1.0f + sq);
    #pragma unroll
    for (int d = 0; d < 16; ++d) vv[d] *= scale;
    #pragma unroll
    for (int q = 0; q < 4; ++q) {
        float4 o = make_float4(vv[4*q], vv[4*q+1], vv[4*q+2], vv[4*q+3]);
        *reinterpret_cast<float4*>(&v[(size_t)p * 512 + m * 16 + q * 4]) = o;
    }
    if (VB2) {
        int MT = m >> 1, u = m & 1;
        #pragma unroll
        for (int g2 = 0; g2 < 2; ++g2) {
            uint4 o;
            o.x = pk2(vv[4*g2+0], vv[4*g2+1]);
            o.y = pk2(vv[4*g2+2], vv[4*g2+3]);
            o.z = pk2(vv[8+4*g2+0], vv[8+4*g2+1]);
            o.w = pk2(vv[8+4*g2+2], vv[8+4*g2+3]);
            vb2[(size_t)(((MT*2+g2)*2 + u)) * 3600 + p] = o;
        }
    }
    float mu = 0.f;
    #pragma unroll
    for (int d = 0; d < 16; ++d) mu += vv[d];
    mu *= (1.0f / 16.0f);
    float var = 0.f;
    #pragma unroll
    for (int d = 0; d < 16; ++d) { float c = vv[d] - mu; var = fmaf(c, c, var); }
    var *= (1.0f / 16.0f);
    float rstd = rsqrtf(var + 1e-5f);
    int b = p / 225, hw = p - b * 225;
    size_t ob = (size_t)OUTOFF + (size_t)b * 115200 + (size_t)m * 3600 + (size_t)hw * 16;
    #pragma unroll
    for (int q = 0; q < 4; ++q) {
        float4 o;
        o.x = (vv[4*q+0] - mu) * rstd * gamma[4*q+0] + beta[4*q+0];
        o.y = (vv[4*q+1] - mu) * rstd * gamma[4*q+1] + beta[4*q+1];
        o.z = (vv[4*q+2] - mu) * rstd * gamma[4*q+2] + beta[4*q+2];
        o.w = (vv[4*q+3] - mu) * rstd * gamma[4*q+3] + beta[4*q+3];
        *reinterpret_cast<float4*>(&out[ob + 4 * q]) = o;
    }
}

// ---------------------------------------------------------------------------
// nqk: block = (128 p, 18 chunks). 4 waves, wave = one 32-p subtile.
// v held in 128 VGPRs/lane; wt chunk staged in LDS (dbuf, 64KB) shared by
// all waves; patch frags direct-global; epilogue in-lane dot + shfl_xor(32).
// grid (29, 16).
// ---------------------------------------------------------------------------
template<bool VB2>
__global__ __launch_bounds__(256, 2) void nqk_mfma(
    const int4* __restrict__ x2, const int4* __restrict__ wt,
    const float* __restrict__ vsrc, const uint4* __restrict__ vb2,
    float* __restrict__ out)
{
    __shared__ int4 As[2][2048];   // [buf][sg*512 + md]
    const int t  = threadIdx.x;
    const int l  = t & 63, wv = t >> 6;
    const int g2 = l >> 5, lp = l & 31;
    const int P0 = blockIdx.x * 128;
    const int c0 = blockIdx.y * 18;
    const int wbase = t & ~63;

    const int p = P0 + wv * 32 + lp;
    const bool pval = p < P_TOTAL;
    const int pc = pval ? p : 0;
    const int bb = pc / 225, rem = pc - bb * 225;
    const int ho = rem / 15, wo = rem - ho * 15;
    const int px = bb * 32768 + ho * 64 + wo * 2;
    const size_t ob = (size_t)bb * 2073600 + ho * 15 + wo;

    // ---- v preload: 32 x 16B per lane ----
    uint4 vr[16][2];
    if (VB2) {
        #pragma unroll
        for (int MT = 0; MT < 16; ++MT)
            #pragma unroll
            for (int u = 0; u < 2; ++u)
                vr[MT][u] = vb2[(size_t)(((MT*2+g2)*2 + u)) * 3600 + pc];
    } else {
        #pragma unroll
        for (int MT = 0; MT < 16; ++MT)
            #pragma unroll
            for (int u = 0; u < 2; ++u) {
                const float* vp = vsrc + (size_t)pc * 512 + (MT*2+u) * 16;
                float4 q0 = *(const float4*)(vp + 4*g2);
                float4 q1 = *(const float4*)(vp + 8 + 4*g2);
                uint4 r;
                r.x = pk2(q0.x, q0.y); r.y = pk2(q0.z, q0.w);
                r.z = pk2(q1.x, q1.y); r.w = pk2(q1.z, q1.w);
                vr[MT][u] = r;
            }
    }

    auto STAGE = [&](int b, int c) {
        const int4* src = wt + (size_t)c * 2048;
        #pragma unroll
        for (int k = 0; k < 8; ++k)
            gload16(src + k*256 + t, &As[b][k*256 + wbase]);
    };
    auto LOADB = [&](int c, s8v& BhO, s8v& BlO) {
        int n = c & 31, kl = c >> 5;
        int kk = kl / 3, ll = kl - kk * 3;
        size_t bi = (size_t)(px + n*1024 + kk*32 + ll) * 4 + g2;
        BhO = __builtin_bit_cast(s8v, x2[bi]);
        BlO = __builtin_bit_cast(s8v, x2[bi + 2]);
    };

    STAGE(0, c0);
    s8v Bh, Bl;
    LOADB(c0, Bh, Bl);
    int buf = 0;
    for (int ci = 0; ci < 18; ++ci) {
        int c = c0 + ci;
        __syncthreads();
        if (ci + 1 < 18) STAGE(buf ^ 1, c + 1);
        s8v Bhn = Bh, Bln = Bl;
        if (ci + 1 < 18) LOADB(c + 1, Bhn, Bln);

        int n = c & 31, kl = c >> 5;
        int kk = kl / 3, ll = kl - kk * 3;
        size_t koff = (size_t)n * 64800 + (size_t)kk * 21600 + (size_t)ll * 7200;

        #pragma unroll
        for (int MT = 0; MT < 16; ++MT) {
            s8v Ah = __builtin_bit_cast(s8v, As[buf][g2*512 + MT*32 + lp]);
            s8v Al = __builtin_bit_cast(s8v, As[buf][(2+g2)*512 + MT*32 + lp]);
            f16v acc = 0.0f;
            acc = __builtin_amdgcn_mfma_f32_32x32x16_bf16(Al, Bh, acc, 0, 0, 0);
            acc = __builtin_amdgcn_mfma_f32_32x32x16_bf16(Ah, Bl, acc, 0, 0, 0);
            acc = __builtin_amdgcn_mfma_f32_32x32x16_bf16(Ah, Bh, acc, 0, 0, 0);
            uint4 a0 = vr[MT][0], a1 = vr[MT][1];
            float s0, s1;
            s0 = acc[0] * bflo(a0.x);
            s0 = fmaf(acc[1], bfhi(a0.x), s0);
            s0 = fmaf(acc[2], bflo(a0.y), s0);
            s0 = fmaf(acc[3], bfhi(a0.y), s0);
            s0 = fmaf(acc[4], bflo(a0.z), s0);
            s0 = fmaf(acc[5], bfhi(a0.z), s0);
            s0 = fmaf(acc[6], bflo(a0.w), s0);
            s0 = fmaf(acc[7], bfhi(a0.w), s0);
            s1 = acc[8] * bflo(a1.x);
            s1 = fmaf(acc[9],  bfhi(a1.x), s1);
            s1 = fmaf(acc[10], bflo(a1.y), s1);
            s1 = fmaf(acc[11], bfhi(a1.y), s1);
            s1 = fmaf(acc[12], bflo(a1.z), s1);
            s1 = fmaf(acc[13], bfhi(a1.z), s1);
            s1 = fmaf(acc[14], bflo(a1.w), s1);
            s1 = fmaf(acc[15], bfhi(a1.w), s1);
            float r0 = s0 + __shfl_xor(s0, 32);
            float r1 = s1 + __shfl_xor(s1, 32);
            if (pval)
                out[ob + koff + (size_t)(MT*2 + g2) * 225] = g2 ? r1 : r0;
        }
        Bh = Bhn; Bl = Bln; buf ^= 1;
    }
}

// ---------------------------------------------------------------------------
extern "C" void kernel_launch(void* const* d_in, const int* in_sizes, int n_in,
                              void* d_out, int out_size, void* d_ws, size_t ws_size,
                              hipStream_t stream)
{
    const float* x     = (const float*)d_in[0];
    const float* w     = (const float*)d_in[1];
    const float* gamma = (const float*)d_in[2];
    const float* beta  = (const float*)d_in[3];
    float* out = (float*)d_out;
    char* ws = (char*)d_ws;

    float* vws = (float*)(ws + V_OFF);
    int4*  wt  = (int4*)(ws + WT_OFF);
    int4*  x2  = (int4*)(ws + X2_OFF);
    uint4* vb2 = (uint4*)(ws + VB2_OFF);
    bool use_vb2 = ws_size >= WS_VB2_NEED;

    conv_x_kernel<<<2048, 256, 0, stream>>>(x, x2);
    conv_w_kernel<<<288, 256, 0, stream>>>(w, wt);
    gemm_v_mfma<<<dim3(4, 29), 256, 0, stream>>>(x2, wt, vws);
    if (use_vb2) {
        squash_ln_kernel<true><<<450, 256, 0, stream>>>(vws, gamma, beta, out, vb2);
        nqk_mfma<true><<<dim3(29, 16), 256, 0, stream>>>(x2, wt, vws, vb2, out);
    } else {
        squash_ln_kernel<false><<<450, 256, 0, stream>>>(vws, gamma, beta, out, vb2);
        nqk_mfma<false><<<dim3(29, 16), 256, 0, stream>>>(x2, wt, vws, vb2, out);
    }
}